// Round 1
// baseline (436.062 us; speedup 1.0000x reference)
//
#include <hip/hip_runtime.h>

// FCNNRhoValuationFunction: rho = sqrt((z2c0-z1c0)^2 + (z1c2-z2c2)^2),
// dist_id = #{k in 1..9 : rho >= k*0.1f}, out[b] = dist_grade[b][dist_id].
// Memory-bound: all cache lines of all inputs are needed (gaps < 64B).
// IEEE ops (__f*_rn) to stay bit-identical to the numpy f32 reference:
// a 1-ulp difference can flip a threshold compare and change out by O(1),
// far above the 2e-2 absmax gate.

#define ZD 11
#define GD 10

__global__ __launch_bounds__(256) void rho_valuation_kernel(
    const float* __restrict__ z1,
    const float* __restrict__ z2,
    const float* __restrict__ dg,
    float* __restrict__ out,
    int B)
{
    int b = blockIdx.x * blockDim.x + threadIdx.x;
    if (b >= B) return;

    long off = (long)b * ZD;
    float a0 = z1[off + 0];
    float a2 = z1[off + 2];
    float c0 = z2[off + 0];
    float c2 = z2[off + 2];

    // dx = z2c0 - z1c0 ; dy = -(z2c2 - z1c2) = z1c2 - z2c2 (exact)
    float dx = __fadd_rn(c0, -a0);
    float dy = __fadd_rn(a2, -c2);

    // No fma contraction: mul, mul, add, then correctly-rounded sqrt —
    // bit-identical to numpy f32.
    float s   = __fadd_rn(__fmul_rn(dx, dx), __fmul_rn(dy, dy));
    float rho = __fsqrt_rn(s);

    int id = 0;
    #pragma unroll
    for (int k = 1; k <= 9; ++k) {
        // (float)k * 0.1f constant-folded with IEEE f32 rounding,
        // matching np.arange(1,10,f32) * 0.1 under NEP-50 promotion.
        id += (rho >= (float)k * 0.1f) ? 1 : 0;
    }

    out[b] = dg[(long)b * GD + id];
}

extern "C" void kernel_launch(void* const* d_in, const int* in_sizes, int n_in,
                              void* d_out, int out_size, void* d_ws, size_t ws_size,
                              hipStream_t stream) {
    const float* z1 = (const float*)d_in[0];
    const float* z2 = (const float*)d_in[1];
    const float* dg = (const float*)d_in[2];
    float* out = (float*)d_out;

    int B = out_size;  // 4,000,000
    const int block = 256;
    int grid = (B + block - 1) / block;
    rho_valuation_kernel<<<grid, block, 0, stream>>>(z1, z2, dg, out, B);
}

// Round 2
// 431.134 us; speedup vs baseline: 1.0114x; 1.0114x over previous
//
#include <hip/hip_runtime.h>

// FCNNRhoValuationFunction: rho = sqrt((z2c0-z1c0)^2 + (z1c2-z2c2)^2),
// dist_id = #{k in 1..9 : rho >= k*0.1f}, out[b] = dist_grade[b][dist_id].
//
// R1 showed 154 us @ 22% HBM peak with scalar strided gathers (stride 44/40 B
// -> ~44 cache lines per wave load instruction; TA-serialization bound).
// R2: stage full rows into LDS with coalesced float4 loads, then read the
// needed scalars from LDS. All global traffic becomes 16 B/lane coalesced.
//
// IEEE ops (__f*_rn) keep us bit-identical to the numpy f32 reference:
// a 1-ulp diff can flip a threshold compare and change out by O(1) >> 2e-2.

#define ZD 11
#define GD 10
#define ROWS 256  // rows per block == blockDim.x

__global__ __launch_bounds__(256) void rho_valuation_kernel(
    const float* __restrict__ z1,
    const float* __restrict__ z2,
    const float* __restrict__ dg,
    float* __restrict__ out,
    int B)
{
    __shared__ float s_z1[ROWS * ZD];   // 11264 B
    __shared__ float s_z2[ROWS * ZD];   // 11264 B
    __shared__ float s_dg[ROWS * GD];   // 10240 B

    const int t = threadIdx.x;
    const long base = (long)blockIdx.x * ROWS;

    if (base + ROWS <= B) {
        // ---- fast path: full block of 256 rows, coalesced float4 staging ----
        // Byte offsets: base*ZD*4 = blk*11264, base*GD*4 = blk*10240 -> 16B aligned.
        const float4* g1 = (const float4*)(z1 + base * ZD);
        const float4* g2 = (const float4*)(z2 + base * ZD);
        const float4* g3 = (const float4*)(dg + base * GD);
        float4* l1 = (float4*)s_z1;
        float4* l2 = (float4*)s_z2;
        float4* l3 = (float4*)s_dg;

        #pragma unroll
        for (int i = 0; i < 3; ++i) {           // 704 float4 = 2.75 * 256
            int idx = t + i * 256;
            if (idx < (ROWS * ZD) / 4) { l1[idx] = g1[idx]; l2[idx] = g2[idx]; }
        }
        #pragma unroll
        for (int i = 0; i < 3; ++i) {           // 640 float4 = 2.5 * 256
            int idx = t + i * 256;
            if (idx < (ROWS * GD) / 4) { l3[idx] = g3[idx]; }
        }
        __syncthreads();

        float a0 = s_z1[t * ZD + 0];
        float a2 = s_z1[t * ZD + 2];
        float c0 = s_z2[t * ZD + 0];
        float c2 = s_z2[t * ZD + 2];

        float dx = __fadd_rn(c0, -a0);
        float dy = __fadd_rn(a2, -c2);
        float s   = __fadd_rn(__fmul_rn(dx, dx), __fmul_rn(dy, dy));
        float rho = __fsqrt_rn(s);

        int id = 0;
        #pragma unroll
        for (int k = 1; k <= 9; ++k)
            id += (rho >= (float)k * 0.1f) ? 1 : 0;

        out[base + t] = s_dg[t * GD + id];
    } else {
        // ---- tail path (block-uniform branch): scalar per-row ----
        long b = base + t;
        if (b < B) {
            float a0 = z1[b * ZD + 0];
            float a2 = z1[b * ZD + 2];
            float c0 = z2[b * ZD + 0];
            float c2 = z2[b * ZD + 2];
            float dx = __fadd_rn(c0, -a0);
            float dy = __fadd_rn(a2, -c2);
            float s   = __fadd_rn(__fmul_rn(dx, dx), __fmul_rn(dy, dy));
            float rho = __fsqrt_rn(s);
            int id = 0;
            #pragma unroll
            for (int k = 1; k <= 9; ++k)
                id += (rho >= (float)k * 0.1f) ? 1 : 0;
            out[b] = dg[b * GD + id];
        }
    }
}

extern "C" void kernel_launch(void* const* d_in, const int* in_sizes, int n_in,
                              void* d_out, int out_size, void* d_ws, size_t ws_size,
                              hipStream_t stream) {
    const float* z1 = (const float*)d_in[0];
    const float* z2 = (const float*)d_in[1];
    const float* dg = (const float*)d_in[2];
    float* out = (float*)d_out;

    int B = out_size;  // 4,000,000 (divisible by 256 -> 15625 full blocks)
    const int block = ROWS;
    int grid = (B + block - 1) / block;
    rho_valuation_kernel<<<grid, block, 0, stream>>>(z1, z2, dg, out, B);
}